// Round 17
// baseline (331.725 us; speedup 1.0000x reference)
//
#include <hip/hip_runtime.h>

#define BATCH 8
#define NROW  2048
#define NF    64
#define JSPLIT 4
#define JPB   (NROW / JSPLIT)               // 512 k per z-slice
#define CHUNK 64
#define TOT   ((size_t)BATCH * NROW * NF)   // 1048576
#define NB    1024                          // fused grid (4 blocks/CU exact)

typedef float    f32x4 __attribute__((ext_vector_type(4)));
typedef _Float16 f16x8 __attribute__((ext_vector_type(8)));
typedef unsigned short u16x8 __attribute__((ext_vector_type(8)));

union fragh { u16x8 u; f16x8 h; };
union hbits { _Float16 h; unsigned short u; };

#define ASCALE 4096.0f     // 2^12
#define XSCALE 2048.0f     // 2^11
#define THRESH 4194304.0   // 0.5 * 2^23

#define AS1 __attribute__((address_space(1)))
#define AS3 __attribute__((address_space(3)))

__device__ __forceinline__ void gld16u(const unsigned short* g, unsigned short* l) {
  __builtin_amdgcn_global_load_lds((const AS1 void*)g, (AS3 void*)l, 16, 0, 0);
}

// device-scope grid barrier; counters zeroed via hipMemsetAsync each launch
__device__ __forceinline__ void grid_barrier(unsigned* cnt, unsigned nb) {
  __syncthreads();
  if (threadIdx.x == 0) {
    __threadfence();   // release prior writes (device scope)
    __hip_atomic_fetch_add(cnt, 1u, __ATOMIC_ACQ_REL, __HIP_MEMORY_SCOPE_AGENT);
    while (__hip_atomic_load(cnt, __ATOMIC_ACQUIRE, __HIP_MEMORY_SCOPE_AGENT) < nb)
      __builtin_amdgcn_s_sleep(8);
    __threadfence();   // acquire
  }
  __syncthreads();
}

// split 8 scaled f32 -> 2 f16 fragments (RNE; residual exact) [proven r15-r16]
__device__ __forceinline__ void split8h(const f32x4 q0, const f32x4 q1,
                                        fragh* Af) {
  float av[8];
  *(f32x4*)&av[0] = q0;
  *(f32x4*)&av[4] = q1;
  f16x8 h0, h1;
#pragma unroll
  for (int e = 0; e < 8; ++e) {
    const float v = av[e] * ASCALE;
    const _Float16 b0 = (_Float16)v;
    const float r = v - (float)b0;        // exact
    h0[e] = b0;
    h1[e] = (_Float16)r;
  }
  Af[0].h = h0; Af[1].h = h1;
}

// ---- fused persistent kernel: prep -> barrier -> gemm -> barrier -> combine
// All data slices (xs, wp) are produced and consumed by blocks with the same
// flat&7 == batch == XCD  -> no cross-XCD data visibility needed; only the
// barrier counters cross XCDs (device-scope atomics).
__global__ __launch_bounds__(256, 4)
void fused_gnn(const float* __restrict__ xg, const float* __restrict__ ag,
               float* __restrict__ outg, unsigned short* __restrict__ xs,
               float* __restrict__ wp, unsigned* __restrict__ bar) {
  __shared__ __align__(16) unsigned char smem[2 * 2 * 64 * CHUNK * 2];  // 32 KB

  const int tid  = threadIdx.x;
  const int flat = blockIdx.x;
  const int b    = flat & 7;                      // batch == XCD everywhere

  // ================= phase A: prep x (blocks 0..255) =================
  if (flat < 256) {
    float (*t)[65] = (float(*)[65])smem;          // 64x65 f32 = 16.6 KB
    const int jt = flat >> 3;                     // 0..31
    const int j0 = jt * 64;
    const int l  = tid & 63;
    const int g  = tid >> 6;
    const float* src = xg + ((size_t)b * NROW + j0) * NF;
#pragma unroll
    for (int k = 0; k < 16; ++k) {
      const int j = g * 16 + k;
      t[j][l] = src[(size_t)j * NF + l];
    }
    __syncthreads();
#pragma unroll
    for (int k = 0; k < 16; ++k) {
      const int f = g * 16 + k;
      const float v = t[l][f] * XSCALE;
      hbits b0, b1;
      b0.h = (_Float16)v;
      const float r = v - (float)b0.h;            // exact
      b1.h = (_Float16)r;
      const size_t o = ((size_t)b * NF + f) * NROW + j0 + l;
      xs[o]       = b0.u;
      xs[o + TOT] = b1.u;
    }
  }

  grid_barrier(&bar[0], NB);

  // ================= phase B: gemm (r16 structure, verbatim) =================
  {
    unsigned short (*sB)[2 * 64 * CHUNK] = (unsigned short(*)[2 * 64 * CHUNK])smem;

    const int ln   = tid & 63;
    const int wv   = tid >> 6;
    const int ln15 = ln & 15;
    const int g    = ln >> 4;
    const int bkey = ln15 & 7;

    const int rr = flat >> 3;
    const int bx = rr & 31;
    const int z  = (rr >> 5) & 3;
    const int i0 = bx * 64;
    const int jb = z * JPB;
    const int nch = JPB / CHUNK;                  // 8

    const float* aA =
        ag + ((size_t)b * NROW + i0 + wv * 16 + ln15) * NROW + jb + g * 8;
    const unsigned short* xB = xs + (size_t)b * NF * NROW;

    auto stageB = [&](int buf, int j0) {
#pragma unroll
      for (int lvl = 0; lvl < 2; ++lvl)
#pragma unroll
        for (int h = 0; h < 2; ++h) {
          const int s = h * 256 + tid;
          const int n = s >> 3;
          const int q = (s & 7) ^ (n & 7);
          gld16u(xB + (size_t)lvl * TOT + (size_t)n * NROW + j0 + q * 8,
                 &sB[buf][0] + (lvl * 512 + h * 256 + wv * 64) * 8);
        }
    };

    double macc[4][4];
#pragma unroll
    for (int i = 0; i < 4; ++i)
#pragma unroll
      for (int j = 0; j < 4; ++j) macc[i][j] = 0.0;

    constexpr int AI[4] = {1, 1, 0, 0};
    constexpr int BI[4] = {1, 0, 1, 0};

    stageB(0, jb);
    f32x4 A0 = *(const f32x4*)(aA);
    f32x4 A1 = *(const f32x4*)(aA + 4);
    f32x4 A2 = *(const f32x4*)(aA + 32);
    f32x4 A3 = *(const f32x4*)(aA + 36);

#pragma unroll 1
    for (int t = 0; t < nch; ++t) {
      __syncthreads();
      if (t + 1 < nch) stageB((t + 1) & 1, jb + (t + 1) * CHUNK);
      const int tn = (t + 1 < nch) ? (t + 1) : t;
      const float* aNxt = aA + (size_t)tn * CHUNK;
      f32x4 N0 = *(const f32x4*)(aNxt);
      f32x4 N1 = *(const f32x4*)(aNxt + 4);
      f32x4 N2 = *(const f32x4*)(aNxt + 32);
      f32x4 N3 = *(const f32x4*)(aNxt + 36);

      const unsigned short* sBb = &sB[t & 1][0];
      f32x4 c[4];
#pragma unroll
      for (int nt = 0; nt < 4; ++nt) c[nt] = (f32x4){0.f, 0.f, 0.f, 0.f};

#pragma unroll
      for (int sub = 0; sub < 2; ++sub) {
        fragh Af[2];
        split8h(sub ? A2 : A0, sub ? A3 : A1, Af);

        const int bq = (sub * 4 + g) ^ bkey;
#pragma unroll
        for (int ng = 0; ng < 2; ++ng) {
          fragh Bv[2][2];
#pragma unroll
          for (int nn = 0; nn < 2; ++nn) {
            const int ncol = (ng * 2 + nn) * 16 + ln15;
#pragma unroll
            for (int lvl = 0; lvl < 2; ++lvl)
              Bv[nn][lvl].u =
                  *(const u16x8*)(sBb + lvl * 4096 + ncol * 64 + bq * 8);
          }
#pragma unroll
          for (int term = 0; term < 4; ++term)
#pragma unroll
            for (int nn = 0; nn < 2; ++nn) {
              const int nt = ng * 2 + nn;
              c[nt] = __builtin_amdgcn_mfma_f32_16x16x32_f16(
                  Af[AI[term]].h, Bv[nn][BI[term]].h, c[nt], 0, 0, 0);
            }
        }
      }
      A0 = N0; A1 = N1; A2 = N2; A3 = N3;

#pragma unroll
      for (int nt = 0; nt < 4; ++nt) {
        macc[nt][0] += (double)c[nt].x;
        macc[nt][1] += (double)c[nt].y;
        macc[nt][2] += (double)c[nt].z;
        macc[nt][3] += (double)c[nt].w;
      }
    }

    float* wb = wp + (size_t)z * TOT;
#pragma unroll
    for (int nt = 0; nt < 4; ++nt)
#pragma unroll
      for (int r = 0; r < 4; ++r)
        wb[((size_t)b * NROW + i0 + wv * 16 + g * 4 + r) * NF + nt * 16 + ln15] =
            (float)macc[nt][r];
  }

  grid_barrier(&bar[1], NB);

  // ================= phase C: combine + threshold (L2-hot wp) =================
  {
    const size_t e = ((size_t)b << 17) + (size_t)(flat >> 3) * 1024 +
                     (size_t)tid * 4;
    f32x4 p0 = *(const f32x4*)(wp + e);
    f32x4 p1 = *(const f32x4*)(wp + e + TOT);
    f32x4 p2 = *(const f32x4*)(wp + e + 2 * TOT);
    f32x4 p3 = *(const f32x4*)(wp + e + 3 * TOT);
    f32x4 o;
    o.x = (((double)p0.x + p1.x + p2.x + p3.x) > THRESH) ? 1.0f : 0.0f;
    o.y = (((double)p0.y + p1.y + p2.y + p3.y) > THRESH) ? 1.0f : 0.0f;
    o.z = (((double)p0.z + p1.z + p2.z + p3.z) > THRESH) ? 1.0f : 0.0f;
    o.w = (((double)p0.w + p1.w + p2.w + p3.w) > THRESH) ? 1.0f : 0.0f;
    *(f32x4*)(outg + e) = o;
  }
}

// ---------------- fallback path (ws too small): r16 3-pass ----------------
__global__ __launch_bounds__(256, 4)
void prep_x(const float* __restrict__ xg, unsigned short* __restrict__ xs) {
  __shared__ float t[64][65];
  const int b  = blockIdx.y;
  const int j0 = blockIdx.x * 64;
  const int l  = threadIdx.x & 63;
  const int g  = threadIdx.x >> 6;
  const float* src = xg + ((size_t)b * NROW + j0) * NF;
#pragma unroll
  for (int k = 0; k < 16; ++k) {
    const int j = g * 16 + k;
    t[j][l] = src[(size_t)j * NF + l];
  }
  __syncthreads();
#pragma unroll
  for (int k = 0; k < 16; ++k) {
    const int f = g * 16 + k;
    const float v = t[l][f] * XSCALE;
    hbits b0, b1;
    b0.h = (_Float16)v;
    const float r = v - (float)b0.h;
    b1.h = (_Float16)r;
    const size_t o = ((size_t)b * NF + f) * NROW + j0 + l;
    xs[o]       = b0.u;
    xs[o + TOT] = b1.u;
  }
}

__global__ __launch_bounds__(256, 4)
void gemm_direct(const float* __restrict__ ag, const unsigned short* __restrict__ xs,
                 float* __restrict__ outg) {
  __shared__ __align__(16) unsigned short sB[2][2 * 64 * CHUNK];

  const int tid  = threadIdx.x;
  const int ln   = tid & 63;
  const int wv   = tid >> 6;
  const int ln15 = ln & 15;
  const int g    = ln >> 4;
  const int bkey = ln15 & 7;

  const int flat = blockIdx.x;
  const int b    = flat & 7;
  const int bx   = (flat >> 3) & 31;
  const int i0   = bx * 64;
  const int nch  = NROW / CHUNK;

  const float* aA =
      ag + ((size_t)b * NROW + i0 + wv * 16 + ln15) * NROW + g * 8;
  const unsigned short* xB = xs + (size_t)b * NF * NROW;

  auto stageB = [&](int buf, int j0) {
#pragma unroll
    for (int lvl = 0; lvl < 2; ++lvl)
#pragma unroll
      for (int h = 0; h < 2; ++h) {
        const int s = h * 256 + tid;
        const int n = s >> 3;
        const int q = (s & 7) ^ (n & 7);
        gld16u(xB + (size_t)lvl * TOT + (size_t)n * NROW + j0 + q * 8,
               &sB[buf][0] + (lvl * 512 + h * 256 + wv * 64) * 8);
      }
  };

  double macc[4][4];
#pragma unroll
  for (int i = 0; i < 4; ++i)
#pragma unroll
    for (int j = 0; j < 4; ++j) macc[i][j] = 0.0;

  constexpr int AI[4] = {1, 1, 0, 0};
  constexpr int BI[4] = {1, 0, 1, 0};

  stageB(0, 0);
  f32x4 A0 = *(const f32x4*)(aA);
  f32x4 A1 = *(const f32x4*)(aA + 4);
  f32x4 A2 = *(const f32x4*)(aA + 32);
  f32x4 A3 = *(const f32x4*)(aA + 36);

#pragma unroll 1
  for (int t = 0; t < nch; ++t) {
    __syncthreads();
    if (t + 1 < nch) stageB((t + 1) & 1, (t + 1) * CHUNK);
    const int tn = (t + 1 < nch) ? (t + 1) : t;
    const float* aNxt = aA + (size_t)tn * CHUNK;
    f32x4 N0 = *(const f32x4*)(aNxt);
    f32x4 N1 = *(const f32x4*)(aNxt + 4);
    f32x4 N2 = *(const f32x4*)(aNxt + 32);
    f32x4 N3 = *(const f32x4*)(aNxt + 36);

    const unsigned short* sBb = &sB[t & 1][0];
    f32x4 c[4];
#pragma unroll
    for (int nt = 0; nt < 4; ++nt) c[nt] = (f32x4){0.f, 0.f, 0.f, 0.f};

#pragma unroll
    for (int sub = 0; sub < 2; ++sub) {
      fragh Af[2];
      split8h(sub ? A2 : A0, sub ? A3 : A1, Af);
      const int bq = (sub * 4 + g) ^ bkey;
#pragma unroll
      for (int ng = 0; ng < 2; ++ng) {
        fragh Bv[2][2];
#pragma unroll
        for (int nn = 0; nn < 2; ++nn) {
          const int ncol = (ng * 2 + nn) * 16 + ln15;
#pragma unroll
          for (int lvl = 0; lvl < 2; ++lvl)
            Bv[nn][lvl].u =
                *(const u16x8*)(sBb + lvl * 4096 + ncol * 64 + bq * 8);
        }
#pragma unroll
        for (int term = 0; term < 4; ++term)
#pragma unroll
          for (int nn = 0; nn < 2; ++nn) {
            const int nt = ng * 2 + nn;
            c[nt] = __builtin_amdgcn_mfma_f32_16x16x32_f16(
                Af[AI[term]].h, Bv[nn][BI[term]].h, c[nt], 0, 0, 0);
          }
      }
    }
    A0 = N0; A1 = N1; A2 = N2; A3 = N3;
#pragma unroll
    for (int nt = 0; nt < 4; ++nt) {
      macc[nt][0] += (double)c[nt].x;
      macc[nt][1] += (double)c[nt].y;
      macc[nt][2] += (double)c[nt].z;
      macc[nt][3] += (double)c[nt].w;
    }
  }

#pragma unroll
  for (int nt = 0; nt < 4; ++nt)
#pragma unroll
    for (int r = 0; r < 4; ++r)
      outg[((size_t)b * NROW + i0 + wv * 16 + g * 4 + r) * NF + nt * 16 + ln15] =
          (macc[nt][r] > THRESH) ? 1.0f : 0.0f;
}

extern "C" void kernel_launch(void* const* d_in, const int* in_sizes, int n_in,
                              void* d_out, int out_size, void* d_ws, size_t ws_size,
                              hipStream_t stream) {
  const float* x = (const float*)d_in[0];
  const float* a = (const float*)d_in[1];
  float* out = (float*)d_out;
  unsigned short* xs = (unsigned short*)d_ws;                     // 4 MB
  float* wp  = (float*)((char*)d_ws + 2 * TOT * sizeof(unsigned short));
  unsigned* bar = (unsigned*)((char*)d_ws + 2 * TOT * sizeof(unsigned short)
                              + (size_t)JSPLIT * TOT * sizeof(float));

  const size_t need = 2 * TOT * sizeof(unsigned short)
                    + (size_t)JSPLIT * TOT * sizeof(float) + 256;  // ~20 MB
  if (ws_size >= need) {
    hipMemsetAsync(bar, 0, 256, stream);
    fused_gnn<<<dim3(NB), dim3(256), 0, stream>>>(x, a, out, xs, wp, bar);
  } else {
    prep_x<<<dim3(NROW / 64, BATCH), dim3(256), 0, stream>>>(x, xs);
    gemm_direct<<<dim3(BATCH * (NROW / 64)), dim3(256), 0, stream>>>(a, xs, out);
  }
}

// Round 18
// 39.864 us; speedup vs baseline: 8.3214x; 8.3214x over previous
//
#include <hip/hip_runtime.h>

#define BATCH 8
#define NROW  2048
#define NF    64
#define JSPLIT 4
#define JPB   (NROW / JSPLIT)               // 512 k per z-slice
#define CHUNK 64
#define TOT   ((size_t)BATCH * NROW * NF)   // 1048576

typedef float    f32x4 __attribute__((ext_vector_type(4)));
typedef _Float16 f16x8 __attribute__((ext_vector_type(8)));
typedef unsigned short u16x8 __attribute__((ext_vector_type(8)));

union fragh { u16x8 u; f16x8 h; };
union hbits { _Float16 h; unsigned short u; };

#define ASCALE 4096.0f     // 2^12  (a in [0,1) -> [0,4096): no f16 denormals)
#define XSCALE 2048.0f     // 2^11  (|x|max ~5.5 -> ~11k < 65504)
#define THRESH 4194304.0   // 0.5 * 2^23 (product scale)

#define AS1 __attribute__((address_space(1)))
#define AS3 __attribute__((address_space(3)))

__device__ __forceinline__ void gld16u(const unsigned short* g, unsigned short* l) {
  __builtin_amdgcn_global_load_lds((const AS1 void*)g, (AS3 void*)l, 16, 0, 0);
}

// ---- pass 1: transpose x, scale, split into 2 f16 levels ----
// grid 256, b = flat&7 == XCD: xs slice produced on its consumer XCD.
__global__ __launch_bounds__(256, 4)
void prep_x(const float* __restrict__ xg, unsigned short* __restrict__ xs) {
  __shared__ float t[64][65];
  const int flat = blockIdx.x;
  const int b  = flat & 7;
  const int j0 = (flat >> 3) * 64;
  const int l  = threadIdx.x & 63;
  const int g  = threadIdx.x >> 6;
  const float* src = xg + ((size_t)b * NROW + j0) * NF;
#pragma unroll
  for (int k = 0; k < 16; ++k) {
    const int j = g * 16 + k;
    t[j][l] = src[(size_t)j * NF + l];
  }
  __syncthreads();
#pragma unroll
  for (int k = 0; k < 16; ++k) {
    const int f = g * 16 + k;
    const float v = t[l][f] * XSCALE;
    hbits b0, b1;
    b0.h = (_Float16)v;
    const float r = v - (float)b0.h;      // exact
    b1.h = (_Float16)r;
    const size_t o = ((size_t)b * NF + f) * NROW + j0 + l;
    xs[o]       = b0.u;
    xs[o + TOT] = b1.u;
  }
}

// split 8 scaled f32 -> 2 f16 fragments (RNE; residual exact) [proven r15-r16]
__device__ __forceinline__ void split8h(const f32x4 q0, const f32x4 q1,
                                        fragh* Af) {
  float av[8];
  *(f32x4*)&av[0] = q0;
  *(f32x4*)&av[4] = q1;
  f16x8 h0, h1;
#pragma unroll
  for (int e = 0; e < 8; ++e) {
    const float v = av[e] * ASCALE;
    const _Float16 b0 = (_Float16)v;
    const float r = v - (float)b0;        // exact
    h0[e] = b0;
    h1[e] = (_Float16)r;
  }
  Af[0].h = h0; Af[1].h = h1;
}

// ---- pass 2: 2-level f16 MFMA GEMM, 8-wave blocks (r16 per-wave pattern) ----
// Block: 512 thr = 8 waves, 128 rows x 64 cols; wave wv -> rows i0+wv*16..+16.
// Per chunk (64 k): ONE 16KB B-stage serves 128 rows (half r16's staging),
// per wave 2 subs x {split8h, 8 ds_read_b128, 16 MFMA}, one barrier, one fold.
// B LDS dbuf 2x16KB, store octet (s&7)^(n&7), read octet (sub*4+g)^(ncol&7).
// A: global->reg prefetch-1 (coalesced). b = flat&7 == XCD.
template <bool DIRECT>
__global__ __launch_bounds__(512, 4)
void gemm_mfma(const float* __restrict__ ag, const unsigned short* __restrict__ xs,
               float* __restrict__ outg, float* __restrict__ wp) {
  __shared__ __align__(16) unsigned short sB[2][2 * 64 * CHUNK];   // 2 x 16KB

  const int tid  = threadIdx.x;
  const int ln   = tid & 63;
  const int wv   = tid >> 6;          // 0..7
  const int ln15 = ln & 15;
  const int g    = ln >> 4;
  const int bkey = ln15 & 7;

  const int flat = blockIdx.x;
  const int b    = flat & 7;                      // batch == XCD
  const int rr   = flat >> 3;
  const int bx   = rr & 15;                       // 16 row-tiles of 128
  const int z    = DIRECT ? 0 : ((rr >> 4) & 3);
  const int i0   = bx * 128;
  const int jb   = z * JPB;
  const int nch  = (DIRECT ? NROW : JPB) / CHUNK;   // 32 or 8

  const float* aA =
      ag + ((size_t)b * NROW + i0 + wv * 16 + ln15) * NROW + jb + g * 8;
  const unsigned short* xB = xs + (size_t)b * NF * NROW;

  // stage B chunk: 2 gld_lds/thread (512 slots per lvl; slot s: row n=s>>3,
  // octet pos p=s&7 holds global octet p^(n&7); linear LDS dest)
  auto stageB = [&](int buf, int j0) {
#pragma unroll
    for (int lvl = 0; lvl < 2; ++lvl) {
      const int n = tid >> 3;
      const int q = (tid & 7) ^ (n & 7);
      gld16u(xB + (size_t)lvl * TOT + (size_t)n * NROW + j0 + q * 8,
             &sB[buf][0] + (lvl * 512 + wv * 64) * 8);
    }
  };

  double macc[4][4];
#pragma unroll
  for (int i = 0; i < 4; ++i)
#pragma unroll
    for (int j = 0; j < 4; ++j) macc[i][j] = 0.0;

  constexpr int AI[4] = {1, 1, 0, 0};
  constexpr int BI[4] = {1, 0, 1, 0};

  stageB(0, jb);
  f32x4 A0 = *(const f32x4*)(aA);          // sub0: k = g*8
  f32x4 A1 = *(const f32x4*)(aA + 4);
  f32x4 A2 = *(const f32x4*)(aA + 32);     // sub1: k = 32 + g*8
  f32x4 A3 = *(const f32x4*)(aA + 36);

#pragma unroll 1
  for (int t = 0; t < nch; ++t) {
    __syncthreads();                  // stage(t) visible; buf^1 free
    if (t + 1 < nch) stageB((t + 1) & 1, jb + (t + 1) * CHUNK);
    const int tn = (t + 1 < nch) ? (t + 1) : t;
    const float* aNxt = aA + (size_t)tn * CHUNK;
    f32x4 N0 = *(const f32x4*)(aNxt);
    f32x4 N1 = *(const f32x4*)(aNxt + 4);
    f32x4 N2 = *(const f32x4*)(aNxt + 32);
    f32x4 N3 = *(const f32x4*)(aNxt + 36);

    const unsigned short* sBb = &sB[t & 1][0];
    f32x4 c[4];
#pragma unroll
    for (int nt = 0; nt < 4; ++nt) c[nt] = (f32x4){0.f, 0.f, 0.f, 0.f};

#pragma unroll
    for (int sub = 0; sub < 2; ++sub) {
      fragh Af[2];
      split8h(sub ? A2 : A0, sub ? A3 : A1, Af);

      const int bq = (sub * 4 + g) ^ bkey;
#pragma unroll
      for (int ng = 0; ng < 2; ++ng) {
        fragh Bv[2][2];
#pragma unroll
        for (int nn = 0; nn < 2; ++nn) {
          const int ncol = (ng * 2 + nn) * 16 + ln15;
#pragma unroll
          for (int lvl = 0; lvl < 2; ++lvl)
            Bv[nn][lvl].u =
                *(const u16x8*)(sBb + lvl * 4096 + ncol * 64 + bq * 8);
        }
#pragma unroll
        for (int term = 0; term < 4; ++term)
#pragma unroll
          for (int nn = 0; nn < 2; ++nn) {
            const int nt = ng * 2 + nn;
            c[nt] = __builtin_amdgcn_mfma_f32_16x16x32_f16(
                Af[AI[term]].h, Bv[nn][BI[term]].h, c[nt], 0, 0, 0);
          }
      }
    }
    A0 = N0; A1 = N1; A2 = N2; A3 = N3;

#pragma unroll
    for (int nt = 0; nt < 4; ++nt) {
      macc[nt][0] += (double)c[nt].x;
      macc[nt][1] += (double)c[nt].y;
      macc[nt][2] += (double)c[nt].z;
      macc[nt][3] += (double)c[nt].w;
    }
  }

  // epilogue: D row = g*4 + r (within 16-tile), col = nt*16 + ln15
  if (DIRECT) {
#pragma unroll
    for (int nt = 0; nt < 4; ++nt)
#pragma unroll
      for (int r = 0; r < 4; ++r)
        outg[((size_t)b * NROW + i0 + wv * 16 + g * 4 + r) * NF + nt * 16 + ln15] =
            (macc[nt][r] > THRESH) ? 1.0f : 0.0f;
  } else {
    float* wb = wp + (size_t)z * TOT;
#pragma unroll
    for (int nt = 0; nt < 4; ++nt)
#pragma unroll
      for (int r = 0; r < 4; ++r)
        wb[((size_t)b * NROW + i0 + wv * 16 + g * 4 + r) * NF + nt * 16 + ln15] =
            (float)macc[nt][r];
  }
}

// ---- pass 3: reduce JSPLIT partials in f64, threshold ----
// grid 1024, b = flat&7 == XCD: reads the partial slice its own XCD's gemm
// blocks just wrote (2 MB < 4 MB L2) -> L2-hot instead of HBM re-fetch.
__global__ __launch_bounds__(256)
void combine_thresh(const float* __restrict__ wsv, float* __restrict__ outg) {
  const int flat = blockIdx.x;
  const int b    = flat & 7;
  const int idx  = flat >> 3;                    // 0..127
  const size_t e = ((size_t)b << 17) + (size_t)idx * 1024 + (size_t)threadIdx.x * 4;
  f32x4 p0 = *(const f32x4*)(wsv + e);
  f32x4 p1 = *(const f32x4*)(wsv + e + TOT);
  f32x4 p2 = *(const f32x4*)(wsv + e + 2 * TOT);
  f32x4 p3 = *(const f32x4*)(wsv + e + 3 * TOT);
  f32x4 o;
  o.x = (((double)p0.x + p1.x + p2.x + p3.x) > THRESH) ? 1.0f : 0.0f;
  o.y = (((double)p0.y + p1.y + p2.y + p3.y) > THRESH) ? 1.0f : 0.0f;
  o.z = (((double)p0.z + p1.z + p2.z + p3.z) > THRESH) ? 1.0f : 0.0f;
  o.w = (((double)p0.w + p1.w + p2.w + p3.w) > THRESH) ? 1.0f : 0.0f;
  *(f32x4*)(outg + e) = o;
}

extern "C" void kernel_launch(void* const* d_in, const int* in_sizes, int n_in,
                              void* d_out, int out_size, void* d_ws, size_t ws_size,
                              hipStream_t stream) {
  const float* x = (const float*)d_in[0];
  const float* a = (const float*)d_in[1];
  float* out = (float*)d_out;
  unsigned short* xs = (unsigned short*)d_ws;                 // 2 levels = 4 MB
  float* wp = (float*)((char*)d_ws + 2 * TOT * sizeof(unsigned short));

  prep_x<<<dim3(256), dim3(256), 0, stream>>>(x, xs);

  const size_t need = 2 * TOT * sizeof(unsigned short)
                    + (size_t)JSPLIT * TOT * sizeof(float);   // 20 MB
  if (ws_size >= need) {
    gemm_mfma<false><<<dim3(JSPLIT * BATCH * (NROW / 128)), dim3(512), 0, stream>>>(
        a, xs, out, wp);
    combine_thresh<<<dim3((unsigned)(TOT / 1024)), dim3(256), 0, stream>>>(wp, out);
  } else {
    gemm_mfma<true><<<dim3(BATCH * (NROW / 128)), dim3(512), 0, stream>>>(
        a, xs, out, nullptr);
  }
}